// Round 1
// baseline (5132.676 us; speedup 1.0000x reference)
//
#include <hip/hip_runtime.h>
#include <stdint.h>

#define USER_NUM 100000
#define ITEM_NUM 200000
#define N_NODES  300000
#define EMB      64
#define NNZ      2000000
#define BATCH    4096

// ---------------- threefry2x32 (exact JAX replica) ----------------
__host__ __device__ inline uint32_t rotl32(uint32_t v, int r) {
    return (v << r) | (v >> (32 - r));
}

__host__ __device__ inline void threefry2x32(uint32_t k0, uint32_t k1,
                                             uint32_t x0, uint32_t x1,
                                             uint32_t& o0, uint32_t& o1) {
    uint32_t k2 = k0 ^ k1 ^ 0x1BD11BDAu;
    x0 += k0; x1 += k1;
#define TF_R(r) { x0 += x1; x1 = rotl32(x1, r); x1 ^= x0; }
    TF_R(13) TF_R(15) TF_R(26) TF_R(6)
    x0 += k1; x1 += k2 + 1u;
    TF_R(17) TF_R(29) TF_R(16) TF_R(24)
    x0 += k2; x1 += k0 + 2u;
    TF_R(13) TF_R(15) TF_R(26) TF_R(6)
    x0 += k0; x1 += k1 + 3u;
    TF_R(17) TF_R(29) TF_R(16) TF_R(24)
    x0 += k1; x1 += k2 + 4u;
    TF_R(13) TF_R(15) TF_R(26) TF_R(6)
    x0 += k2; x1 += k0 + 5u;
#undef TF_R
    o0 = x0; o1 = x1;
}

// JAX uniform [0,1): u = bitcast((bits>>9) | 0x3f800000) - 1.0
__host__ __device__ inline float tf_uniform(uint32_t bits) {
    uint32_t fb = (bits >> 9) | 0x3f800000u;
    return __builtin_bit_cast(float, fb) - 1.0f;
}

// ---------------- kernels ----------------

// vals_eff[e] = emask[e] ? edge_vals[e] * (1/0.9) : 0
__global__ __launch_bounds__(256) void k_edge_vals(const float* __restrict__ ev,
                                                   float* __restrict__ out,
                                                   uint32_t k0, uint32_t k1) {
    int i = blockIdx.x * 256 + threadIdx.x;
    const int HALF = NNZ / 2;
    if (i >= HALF) return;
    uint32_t y0, y1;
    threefry2x32(k0, k1, (uint32_t)i, (uint32_t)(HALF + i), y0, y1);
    const float sf = (float)(1.0 / 0.9);
    out[i]        = (tf_uniform(y0) < 0.9f) ? ev[i] * sf        : 0.0f;
    out[HALF + i] = (tf_uniform(y1) < 0.9f) ? ev[HALF + i] * sf : 0.0f;
}

// Message dropout bitmasks for 3 layers: bit j of layer mask = keep(element j),
// element (n,d) flat j = n*64+d. random_bits pairs (i, i+9.6M).
__global__ __launch_bounds__(256) void k_msg_masks(uint32_t* __restrict__ masks,
                                                   uint32_t a0, uint32_t a1,
                                                   uint32_t b0, uint32_t b1,
                                                   uint32_t c0, uint32_t c1) {
    const int WPH = (N_NODES * EMB) / 64;     // words per half = 300000
    int t = blockIdx.x * 256 + threadIdx.x;
    if (t >= 3 * WPH) return;
    int layer = t / WPH, tt = t - layer * WPH;
    uint32_t k0 = (layer == 0) ? a0 : (layer == 1) ? b0 : c0;
    uint32_t k1 = (layer == 0) ? a1 : (layer == 1) ? b1 : c1;
    const uint32_t half = (uint32_t)(N_NODES * EMB) / 2;  // 9,600,000
    uint32_t lo = 0, hi = 0;
    for (int b = 0; b < 32; ++b) {
        uint32_t i = (uint32_t)(tt * 32 + b);
        uint32_t y0, y1;
        threefry2x32(k0, k1, i, half + i, y0, y1);
        lo |= (uint32_t)(tf_uniform(y0) < 0.9f) << b;
        hi |= (uint32_t)(tf_uniform(y1) < 0.9f) << b;
    }
    uint32_t* m = masks + (size_t)layer * (2 * WPH);
    m[tt] = lo;
    m[WPH + tt] = hi;
}

// side[row] += vals_eff[e] * ego[col]  (16 threads per edge, float4 each)
__global__ __launch_bounds__(256) void k_scatter(const int* __restrict__ erow,
                                                 const int* __restrict__ ecol,
                                                 const float* __restrict__ vals,
                                                 const float* __restrict__ ego,
                                                 float* __restrict__ side) {
    long long tid = (long long)blockIdx.x * 256 + threadIdx.x;
    int e = (int)(tid >> 4);
    int q = (int)(tid & 15);
    if (e >= NNZ) return;
    float v = vals[e];
    if (v == 0.0f) return;
    int r = erow[e], c = ecol[e];
    float4 g = ((const float4*)(ego + (size_t)c * EMB))[q];
    float* dst = side + (size_t)r * EMB + q * 4;
    unsafeAtomicAdd(dst + 0, v * g.x);
    unsafeAtomicAdd(dst + 1, v * g.y);
    unsafeAtomicAdd(dst + 2, v * g.z);
    unsafeAtomicAdd(dst + 3, v * g.w);
}

// Per node row n (one wave): h = leaky_relu(side@Wg + bg + (ego.*side)@Wb + bb)
// then message dropout; write ego in place. Weights live in VGPRs (col per lane).
__global__ __launch_bounds__(256) void k_fused_layer(const float* __restrict__ side,
                                                     float* __restrict__ ego,
                                                     const float* __restrict__ Wg,
                                                     const float* __restrict__ bg,
                                                     const float* __restrict__ Wb,
                                                     const float* __restrict__ bb,
                                                     const uint32_t* __restrict__ mask) {
    int lane = threadIdx.x & 63;
    int wave = (blockIdx.x * blockDim.x + threadIdx.x) >> 6;
    int nwaves = (gridDim.x * blockDim.x) >> 6;
    float wg[64], wb[64];
#pragma unroll
    for (int k = 0; k < 64; ++k) {
        wg[k] = Wg[k * 64 + lane];
        wb[k] = Wb[k * 64 + lane];
    }
    float bgl = bg[lane], bbl = bb[lane];
    const float inv_keep = (float)(1.0 / 0.9);
    for (int n = wave; n < N_NODES; n += nwaves) {
        float s = side[(size_t)n * 64 + lane];
        float e = ego[(size_t)n * 64 + lane];
        float t = e * s;
        float acc1 = bgl, acc2 = bbl;
#pragma unroll
        for (int k = 0; k < 64; ++k) {
            float sk = __builtin_bit_cast(float,
                __builtin_amdgcn_readlane(__builtin_bit_cast(int, s), k));
            float tk = __builtin_bit_cast(float,
                __builtin_amdgcn_readlane(__builtin_bit_cast(int, t), k));
            acc1 = fmaf(sk, wg[k], acc1);
            acc2 = fmaf(tk, wb[k], acc2);
        }
        float h = acc1 + acc2;
        h = (h >= 0.0f) ? h : 0.2f * h;
        uint32_t word = mask[n * 2 + (lane >> 5)];
        bool keep = (word >> (lane & 31)) & 1u;
        ego[(size_t)n * 64 + lane] = keep ? h * inv_keep : 0.0f;
    }
}

__device__ inline float wred64(float v) {
#pragma unroll
    for (int m = 32; m >= 1; m >>= 1) v += __shfl_xor(v, m, 64);
    return v;
}

// Accumulate one 64-dim segment's contribution to per-batch dot/sq sums.
__global__ __launch_bounds__(256) void k_segacc(const float* __restrict__ ua,
                                                const float* __restrict__ ia,
                                                const int* __restrict__ uid,
                                                const int* __restrict__ iid,
                                                const int* __restrict__ nid,
                                                float* __restrict__ dotp,
                                                float* __restrict__ dotn,
                                                float* __restrict__ sqs,
                                                int normalize) {
    int gt = blockIdx.x * 256 + threadIdx.x;
    int w = gt >> 6, lane = gt & 63;
    if (w >= BATCH) return;
    int u = uid[w], p = iid[w], n = nid[w];
    float eu = ua[(size_t)u * EMB + lane];
    float ep = ia[(size_t)p * EMB + lane];
    float en = ia[(size_t)n * EMB + lane];
    if (normalize) {
        float su = wred64(eu * eu);
        float sp = wred64(ep * ep);
        float sn = wred64(en * en);
        eu /= fmaxf(sqrtf(su), 1e-12f);
        ep /= fmaxf(sqrtf(sp), 1e-12f);
        en /= fmaxf(sqrtf(sn), 1e-12f);
    }
    float dp = wred64(eu * ep);
    float dn = wred64(eu * en);
    float s3 = wred64(eu * eu + ep * ep + en * en);
    if (lane == 0) {
        dotp[w] += dp;
        dotn[w] += dn;
        sqs[w]  += s3;
    }
}

__global__ __launch_bounds__(256) void k_finalize(const float* __restrict__ dotp,
                                                  const float* __restrict__ dotn,
                                                  const float* __restrict__ sqs,
                                                  float* __restrict__ out) {
    __shared__ float smf[256], ssq[256];
    int t = threadIdx.x;
    float mf = 0.0f, s = 0.0f;
    for (int b = t; b < BATCH; b += 256) {
        float x = dotp[b] - dotn[b];
        // JAX log_sigmoid(x) = min(x,0) - log1p(exp(-|x|))
        float ls = fminf(x, 0.0f) - log1pf(expf(-fabsf(x)));
        mf += ls;
        s += sqs[b];
    }
    smf[t] = mf; ssq[t] = s;
    __syncthreads();
    for (int off = 128; off > 0; off >>= 1) {
        if (t < off) { smf[t] += smf[t + off]; ssq[t] += ssq[t + off]; }
        __syncthreads();
    }
    if (t == 0) {
        float mf_loss = -smf[0] / (float)BATCH;
        float reg = 0.5f * ssq[0];
        float emb_loss = (float)1e-4 * reg / (float)BATCH;
        out[0] = mf_loss + emb_loss;
        out[1] = mf_loss;
        out[2] = emb_loss;
    }
}

// ---------------- launch ----------------
extern "C" void kernel_launch(void* const* d_in, const int* in_sizes, int n_in,
                              void* d_out, int out_size, void* d_ws, size_t ws_size,
                              hipStream_t stream) {
    const int*   erow  = (const int*)d_in[0];
    const int*   ecol  = (const int*)d_in[1];
    const float* evals = (const float*)d_in[2];
    const float* uemb  = (const float*)d_in[3];
    const float* iemb  = (const float*)d_in[4];
    const int*   uid   = (const int*)d_in[5];
    const int*   iid   = (const int*)d_in[6];
    const int*   nid   = (const int*)d_in[7];
    const float* Wg[3] = {(const float*)d_in[8],  (const float*)d_in[12], (const float*)d_in[16]};
    const float* bg[3] = {(const float*)d_in[9],  (const float*)d_in[13], (const float*)d_in[17]};
    const float* Wb[3] = {(const float*)d_in[10], (const float*)d_in[14], (const float*)d_in[18]};
    const float* bb[3] = {(const float*)d_in[11], (const float*)d_in[15], (const float*)d_in[19]};

    // workspace layout
    float*    ego      = (float*)d_ws;                     // 19.2M f32
    float*    side     = ego + (size_t)N_NODES * EMB;      // 19.2M f32
    float*    vals_eff = side + (size_t)N_NODES * EMB;     // 2M f32
    uint32_t* masks    = (uint32_t*)(vals_eff + NNZ);      // 3*600000 u32
    float*    dotp     = (float*)(masks + 3 * 600000);     // 4096
    float*    dotn     = dotp + BATCH;
    float*    sqs      = dotn + BATCH;
    size_t needed = ((size_t)N_NODES * EMB * 2 + NNZ + 3 * BATCH) * 4 + 3 * 600000 * 4;
    if (ws_size < needed) return;

    // host-side JAX key derivation: key(42) = (0,42)
    uint32_t a0, b0, a1, b1;
    threefry2x32(0u, 42u, 0u, 2u, a0, b0);   // split block 0 -> (x0f, x1f)
    threefry2x32(0u, 42u, 1u, 3u, a1, b1);   // split block 1
    uint32_t knode0 = a0, knode1 = a1;       // k_node = (x0f[0], x0f[1])
    uint32_t kmsg0  = b0, kmsg1  = b1;       // k_msg  = (x1f[0], x1f[1])
    uint32_t mk[6];
    for (uint32_t k = 0; k < 3; ++k)         // fold_in(k_msg, k) = threefry(k_msg,(0,k))
        threefry2x32(kmsg0, kmsg1, 0u, k, mk[2 * k], mk[2 * k + 1]);

    // init: ego = concat(user_emb, item_emb); zero accumulators
    hipMemcpyAsync(ego, uemb, (size_t)USER_NUM * EMB * 4, hipMemcpyDeviceToDevice, stream);
    hipMemcpyAsync(ego + (size_t)USER_NUM * EMB, iemb, (size_t)ITEM_NUM * EMB * 4,
                   hipMemcpyDeviceToDevice, stream);
    hipMemsetAsync(dotp, 0, 3 * BATCH * 4, stream);

    k_edge_vals<<<(NNZ / 2 + 255) / 256, 256, 0, stream>>>(evals, vals_eff, knode0, knode1);
    k_msg_masks<<<(3 * 300000 + 255) / 256, 256, 0, stream>>>(masks, mk[0], mk[1], mk[2],
                                                              mk[3], mk[4], mk[5]);
    // segment 0: raw initial embeddings, no normalization
    k_segacc<<<BATCH * 64 / 256, 256, 0, stream>>>(uemb, iemb, uid, iid, nid,
                                                   dotp, dotn, sqs, 0);

    for (int k = 0; k < 3; ++k) {
        hipMemsetAsync(side, 0, (size_t)N_NODES * EMB * 4, stream);
        k_scatter<<<(int)(((long long)NNZ * 16) / 256), 256, 0, stream>>>(
            erow, ecol, vals_eff, ego, side);
        k_fused_layer<<<1280, 256, 0, stream>>>(side, ego, Wg[k], bg[k], Wb[k], bb[k],
                                                masks + (size_t)k * 600000);
        k_segacc<<<BATCH * 64 / 256, 256, 0, stream>>>(ego, ego + (size_t)USER_NUM * EMB,
                                                       uid, iid, nid, dotp, dotn, sqs, 1);
    }
    k_finalize<<<1, 256, 0, stream>>>(dotp, dotn, sqs, (float*)d_out);
}

// Round 2
// 2287.129 us; speedup vs baseline: 2.2442x; 2.2442x over previous
//
#include <hip/hip_runtime.h>
#include <stdint.h>

#define USER_NUM 100000
#define ITEM_NUM 200000
#define N_NODES  300000
#define EMB      64
#define NNZ      2000000
#define BATCH    4096
#define R1M      1000000u        // NNZ/2, threefry pair offset for edge dropout
#define HALF_MSG 9600000u        // N_NODES*EMB/2, pair offset for msg dropout
#define INVK     1.1111111111111112f  // 1/0.9

// ---------------- threefry2x32 (exact JAX replica) ----------------
__host__ __device__ inline uint32_t rotl32(uint32_t v, int r) {
    return (v << r) | (v >> (32 - r));
}

__host__ __device__ inline void threefry2x32(uint32_t k0, uint32_t k1,
                                             uint32_t x0, uint32_t x1,
                                             uint32_t& o0, uint32_t& o1) {
    uint32_t k2 = k0 ^ k1 ^ 0x1BD11BDAu;
    x0 += k0; x1 += k1;
#define TF_R(r) { x0 += x1; x1 = rotl32(x1, r); x1 ^= x0; }
    TF_R(13) TF_R(15) TF_R(26) TF_R(6)
    x0 += k1; x1 += k2 + 1u;
    TF_R(17) TF_R(29) TF_R(16) TF_R(24)
    x0 += k2; x1 += k0 + 2u;
    TF_R(13) TF_R(15) TF_R(26) TF_R(6)
    x0 += k0; x1 += k1 + 3u;
    TF_R(17) TF_R(29) TF_R(16) TF_R(24)
    x0 += k1; x1 += k2 + 4u;
    TF_R(13) TF_R(15) TF_R(26) TF_R(6)
    x0 += k2; x1 += k0 + 5u;
#undef TF_R
    o0 = x0; o1 = x1;
}

__host__ __device__ inline float tf_uniform(uint32_t bits) {
    uint32_t fb = (bits >> 9) | 0x3f800000u;
    return __builtin_bit_cast(float, fb) - 1.0f;
}

// ---------------- CSR build ----------------
__global__ __launch_bounds__(256) void k_hist(const int* __restrict__ erow,
                                              uint32_t* __restrict__ cnt) {
    int e = blockIdx.x * 256 + threadIdx.x;
    if (e < NNZ) atomicAdd(&cnt[erow[e]], 1u);
}

// in-block exclusive scan; partials[b] = block total
__global__ __launch_bounds__(1024) void k_scan1(uint32_t* __restrict__ cnt,
                                                uint32_t* __restrict__ partials) {
    __shared__ uint32_t sh[1024];
    int t = threadIdx.x;
    int i = blockIdx.x * 1024 + t;
    uint32_t x = (i < N_NODES) ? cnt[i] : 0u;
    sh[t] = x;
    __syncthreads();
    for (int off = 1; off < 1024; off <<= 1) {
        uint32_t y = (t >= off) ? sh[t - off] : 0u;
        __syncthreads();
        sh[t] += y;
        __syncthreads();
    }
    if (i < N_NODES) cnt[i] = sh[t] - x;          // in-block exclusive
    if (t == 1023) partials[blockIdx.x] = sh[t];  // block sum
}

__global__ __launch_bounds__(1024) void k_scan2(uint32_t* __restrict__ partials,
                                                int nblocks) {
    __shared__ uint32_t sh[1024];
    int t = threadIdx.x;
    uint32_t x = (t < nblocks) ? partials[t] : 0u;
    sh[t] = x;
    __syncthreads();
    for (int off = 1; off < 1024; off <<= 1) {
        uint32_t y = (t >= off) ? sh[t - off] : 0u;
        __syncthreads();
        sh[t] += y;
        __syncthreads();
    }
    if (t < nblocks) partials[t] = sh[t] - x;     // exclusive
}

__global__ __launch_bounds__(1024) void k_scan3(uint32_t* __restrict__ cnt,
                                                const uint32_t* __restrict__ partials) {
    int i = blockIdx.x * 1024 + threadIdx.x;
    if (i < N_NODES) cnt[i] += partials[blockIdx.x];
}

// cursor holds exclusive starts; after this kernel cursor[r] == row end offset
__global__ __launch_bounds__(256) void k_place(const int* __restrict__ erow,
                                               uint32_t* __restrict__ cursor,
                                               uint32_t* __restrict__ eidx) {
    int e = blockIdx.x * 256 + threadIdx.x;
    if (e >= NNZ) return;
    int r = erow[e];
    uint32_t pos = atomicAdd(&cursor[r], 1u);
    eidx[pos] = (uint32_t)e;
}

// ---------------- fused layer: gather + GC/BI matmul + leaky + msg dropout --
__global__ __launch_bounds__(256, 2) void k_fused_layer(
        const float* __restrict__ egoOld, float* __restrict__ egoNew,
        const uint32_t* __restrict__ cursor, const uint32_t* __restrict__ eidx,
        const int* __restrict__ ecol, const float* __restrict__ evals,
        const float* __restrict__ Wg, const float* __restrict__ bg,
        const float* __restrict__ Wb, const float* __restrict__ bb,
        uint32_t kn0, uint32_t kn1, uint32_t km0, uint32_t km1) {
    int lane = threadIdx.x & 63;
    int wave = (blockIdx.x * blockDim.x + threadIdx.x) >> 6;
    int nw = (gridDim.x * blockDim.x) >> 6;
    float wg[64], wb[64];
#pragma unroll
    for (int k = 0; k < 64; ++k) {
        wg[k] = Wg[k * 64 + lane];
        wb[k] = Wb[k * 64 + lane];
    }
    float bgl = bg[lane], bbl = bb[lane];

    for (int n = wave; n < N_NODES; n += nw) {
        uint32_t end = cursor[n];
        uint32_t start = (n > 0) ? cursor[n - 1] : 0u;
        float acc = 0.0f;
        for (uint32_t base = start; base < end; base += 64) {
            int m = (int)min(64u, end - base);
            int c = 0; float v = 0.0f;
            if (lane < m) {
                uint32_t ei = eidx[base + lane];
                c = ecol[ei];
                float ev = evals[ei];
                uint32_t x0 = (ei < R1M) ? ei : ei - R1M;
                uint32_t o0, o1;
                threefry2x32(kn0, kn1, x0, x0 + R1M, o0, o1);
                uint32_t bits = (ei < R1M) ? o0 : o1;
                v = (tf_uniform(bits) < 0.9f) ? ev * INVK : 0.0f;
            }
            for (int j0 = 0; j0 < m; j0 += 8) {
                int jm = min(8, m - j0);
                float g[8];
#pragma unroll
                for (int u = 0; u < 8; ++u)
                    if (u < jm) {
                        int cj = __shfl(c, j0 + u, 64);
                        g[u] = egoOld[(size_t)cj * 64 + lane];
                    }
#pragma unroll
                for (int u = 0; u < 8; ++u)
                    if (u < jm) {
                        float vj = __shfl(v, j0 + u, 64);
                        acc = fmaf(vj, g[u], acc);
                    }
            }
        }
        float e = egoOld[(size_t)n * 64 + lane];
        float t = e * acc;
        float a1 = bgl, a2 = bbl;
#pragma unroll
        for (int k = 0; k < 64; ++k) {
            float sk = __builtin_bit_cast(float,
                __builtin_amdgcn_readlane(__builtin_bit_cast(int, acc), k));
            float tk = __builtin_bit_cast(float,
                __builtin_amdgcn_readlane(__builtin_bit_cast(int, t), k));
            a1 = fmaf(sk, wg[k], a1);
            a2 = fmaf(tk, wb[k], a2);
        }
        float h = a1 + a2;
        h = (h >= 0.0f) ? h : 0.2f * h;
        // message dropout on the fly
        uint32_t j = (uint32_t)n * 64u + (uint32_t)lane;
        uint32_t x0 = (j < HALF_MSG) ? j : j - HALF_MSG;
        uint32_t o0, o1;
        threefry2x32(km0, km1, x0, x0 + HALF_MSG, o0, o1);
        uint32_t bits = (j < HALF_MSG) ? o0 : o1;
        bool keep = tf_uniform(bits) < 0.9f;
        egoNew[(size_t)n * 64 + lane] = keep ? h * INVK : 0.0f;
    }
}

// ---------------- batch accumulation & finalize ----------------
__device__ inline float wred64(float v) {
#pragma unroll
    for (int m = 32; m >= 1; m >>= 1) v += __shfl_xor(v, m, 64);
    return v;
}

__global__ __launch_bounds__(256) void k_segacc(const float* __restrict__ ua,
                                                const float* __restrict__ ia,
                                                const int* __restrict__ uid,
                                                const int* __restrict__ iid,
                                                const int* __restrict__ nid,
                                                float* __restrict__ dotp,
                                                float* __restrict__ dotn,
                                                float* __restrict__ sqs,
                                                int normalize) {
    int gt = blockIdx.x * 256 + threadIdx.x;
    int w = gt >> 6, lane = gt & 63;
    if (w >= BATCH) return;
    int u = uid[w], p = iid[w], n = nid[w];
    float eu = ua[(size_t)u * EMB + lane];
    float ep = ia[(size_t)p * EMB + lane];
    float en = ia[(size_t)n * EMB + lane];
    if (normalize) {
        float su = wred64(eu * eu);
        float sp = wred64(ep * ep);
        float sn = wred64(en * en);
        eu /= fmaxf(sqrtf(su), 1e-12f);
        ep /= fmaxf(sqrtf(sp), 1e-12f);
        en /= fmaxf(sqrtf(sn), 1e-12f);
    }
    float dp = wred64(eu * ep);
    float dn = wred64(eu * en);
    float s3 = wred64(eu * eu + ep * ep + en * en);
    if (lane == 0) {
        dotp[w] += dp;
        dotn[w] += dn;
        sqs[w]  += s3;
    }
}

__global__ __launch_bounds__(256) void k_finalize(const float* __restrict__ dotp,
                                                  const float* __restrict__ dotn,
                                                  const float* __restrict__ sqs,
                                                  float* __restrict__ out) {
    __shared__ float smf[256], ssq[256];
    int t = threadIdx.x;
    float mf = 0.0f, s = 0.0f;
    for (int b = t; b < BATCH; b += 256) {
        float x = dotp[b] - dotn[b];
        float ls = fminf(x, 0.0f) - log1pf(expf(-fabsf(x)));
        mf += ls;
        s += sqs[b];
    }
    smf[t] = mf; ssq[t] = s;
    __syncthreads();
    for (int off = 128; off > 0; off >>= 1) {
        if (t < off) { smf[t] += smf[t + off]; ssq[t] += ssq[t + off]; }
        __syncthreads();
    }
    if (t == 0) {
        float mf_loss = -smf[0] / (float)BATCH;
        float reg = 0.5f * ssq[0];
        float emb_loss = (float)1e-4 * reg / (float)BATCH;
        out[0] = mf_loss + emb_loss;
        out[1] = mf_loss;
        out[2] = emb_loss;
    }
}

// ---------------- launch ----------------
extern "C" void kernel_launch(void* const* d_in, const int* in_sizes, int n_in,
                              void* d_out, int out_size, void* d_ws, size_t ws_size,
                              hipStream_t stream) {
    const int*   erow  = (const int*)d_in[0];
    const int*   ecol  = (const int*)d_in[1];
    const float* evals = (const float*)d_in[2];
    const float* uemb  = (const float*)d_in[3];
    const float* iemb  = (const float*)d_in[4];
    const int*   uid   = (const int*)d_in[5];
    const int*   iid   = (const int*)d_in[6];
    const int*   nid   = (const int*)d_in[7];
    const float* Wg[3] = {(const float*)d_in[8],  (const float*)d_in[12], (const float*)d_in[16]};
    const float* bg[3] = {(const float*)d_in[9],  (const float*)d_in[13], (const float*)d_in[17]};
    const float* Wb[3] = {(const float*)d_in[10], (const float*)d_in[14], (const float*)d_in[18]};
    const float* bb[3] = {(const float*)d_in[11], (const float*)d_in[15], (const float*)d_in[19]};

    // workspace layout (162.9 MB total)
    float*    ego0     = (float*)d_ws;                        // 19.2M f32
    float*    ego1     = ego0 + (size_t)N_NODES * EMB;        // 19.2M f32
    uint32_t* cursor   = (uint32_t*)(ego1 + (size_t)N_NODES * EMB); // 300000
    uint32_t* eidx     = cursor + N_NODES;                    // 2M
    uint32_t* partials = eidx + NNZ;                          // 1024
    float*    dotp     = (float*)(partials + 1024);           // 4096
    float*    dotn     = dotp + BATCH;
    float*    sqs      = dotn + BATCH;
    size_t needed = ((size_t)N_NODES * EMB * 2 + N_NODES + NNZ + 1024 + 3 * BATCH) * 4;
    if (ws_size < needed) return;

    // host-side JAX key derivation: key(42) = (0,42)
    uint32_t a0, b0, a1, b1;
    threefry2x32(0u, 42u, 0u, 2u, a0, b0);   // split block 0
    threefry2x32(0u, 42u, 1u, 3u, a1, b1);   // split block 1
    uint32_t knode0 = a0, knode1 = a1;       // k_node
    uint32_t kmsg0  = b0, kmsg1  = b1;       // k_msg
    uint32_t mk[6];
    for (uint32_t k = 0; k < 3; ++k)
        threefry2x32(kmsg0, kmsg1, 0u, k, mk[2 * k], mk[2 * k + 1]);

    // init
    hipMemcpyAsync(ego0, uemb, (size_t)USER_NUM * EMB * 4, hipMemcpyDeviceToDevice, stream);
    hipMemcpyAsync(ego0 + (size_t)USER_NUM * EMB, iemb, (size_t)ITEM_NUM * EMB * 4,
                   hipMemcpyDeviceToDevice, stream);
    hipMemsetAsync(cursor, 0, (size_t)N_NODES * 4, stream);
    hipMemsetAsync(dotp, 0, 3 * BATCH * 4, stream);

    // CSR build
    const int SCAN_BLOCKS = (N_NODES + 1023) / 1024;  // 293
    k_hist<<<(NNZ + 255) / 256, 256, 0, stream>>>(erow, cursor);
    k_scan1<<<SCAN_BLOCKS, 1024, 0, stream>>>(cursor, partials);
    k_scan2<<<1, 1024, 0, stream>>>(partials, SCAN_BLOCKS);
    k_scan3<<<SCAN_BLOCKS, 1024, 0, stream>>>(cursor, partials);
    k_place<<<(NNZ + 255) / 256, 256, 0, stream>>>(erow, cursor, eidx);

    // segment 0: raw initial embeddings, no normalization
    k_segacc<<<BATCH * 64 / 256, 256, 0, stream>>>(uemb, iemb, uid, iid, nid,
                                                   dotp, dotn, sqs, 0);

    float* bufs[2] = {ego0, ego1};
    for (int k = 0; k < 3; ++k) {
        const float* src = bufs[k & 1];
        float*       dst = bufs[(k + 1) & 1];
        k_fused_layer<<<512, 256, 0, stream>>>(src, dst, cursor, eidx, ecol, evals,
                                               Wg[k], bg[k], Wb[k], bb[k],
                                               knode0, knode1, mk[2 * k], mk[2 * k + 1]);
        k_segacc<<<BATCH * 64 / 256, 256, 0, stream>>>(dst, dst + (size_t)USER_NUM * EMB,
                                                       uid, iid, nid, dotp, dotn, sqs, 1);
    }
    k_finalize<<<1, 256, 0, stream>>>(dotp, dotn, sqs, (float*)d_out);
}

// Round 3
// 1297.169 us; speedup vs baseline: 3.9568x; 1.7632x over previous
//
#include <hip/hip_runtime.h>
#include <stdint.h>

#define USER_NUM 100000
#define ITEM_NUM 200000
#define N_NODES  300000
#define EMB      64
#define NNZ      2000000
#define BATCH    4096
#define R1M      1000000u        // NNZ/2, threefry pair offset for edge dropout
#define HALF_MSG 9600000u        // N_NODES*EMB/2, pair offset for msg dropout
#define INVK     1.1111111111111112f  // 1/0.9

// ---------------- threefry2x32 (exact JAX replica) ----------------
__host__ __device__ inline uint32_t rotl32(uint32_t v, int r) {
    return (v << r) | (v >> (32 - r));
}

__host__ __device__ inline void threefry2x32(uint32_t k0, uint32_t k1,
                                             uint32_t x0, uint32_t x1,
                                             uint32_t& o0, uint32_t& o1) {
    uint32_t k2 = k0 ^ k1 ^ 0x1BD11BDAu;
    x0 += k0; x1 += k1;
#define TF_R(r) { x0 += x1; x1 = rotl32(x1, r); x1 ^= x0; }
    TF_R(13) TF_R(15) TF_R(26) TF_R(6)
    x0 += k1; x1 += k2 + 1u;
    TF_R(17) TF_R(29) TF_R(16) TF_R(24)
    x0 += k2; x1 += k0 + 2u;
    TF_R(13) TF_R(15) TF_R(26) TF_R(6)
    x0 += k0; x1 += k1 + 3u;
    TF_R(17) TF_R(29) TF_R(16) TF_R(24)
    x0 += k1; x1 += k2 + 4u;
    TF_R(13) TF_R(15) TF_R(26) TF_R(6)
    x0 += k2; x1 += k0 + 5u;
#undef TF_R
    o0 = x0; o1 = x1;
}

__host__ __device__ inline float tf_uniform(uint32_t bits) {
    uint32_t fb = (bits >> 9) | 0x3f800000u;
    return __builtin_bit_cast(float, fb) - 1.0f;
}

// ---------------- CSR build ----------------
__global__ __launch_bounds__(256) void k_hist(const int* __restrict__ erow,
                                              uint32_t* __restrict__ cnt) {
    int e = blockIdx.x * 256 + threadIdx.x;
    if (e < NNZ) atomicAdd(&cnt[erow[e]], 1u);
}

__global__ __launch_bounds__(1024) void k_scan1(uint32_t* __restrict__ cnt,
                                                uint32_t* __restrict__ partials) {
    __shared__ uint32_t sh[1024];
    int t = threadIdx.x;
    int i = blockIdx.x * 1024 + t;
    uint32_t x = (i < N_NODES) ? cnt[i] : 0u;
    sh[t] = x;
    __syncthreads();
    for (int off = 1; off < 1024; off <<= 1) {
        uint32_t y = (t >= off) ? sh[t - off] : 0u;
        __syncthreads();
        sh[t] += y;
        __syncthreads();
    }
    if (i < N_NODES) cnt[i] = sh[t] - x;
    if (t == 1023) partials[blockIdx.x] = sh[t];
}

__global__ __launch_bounds__(1024) void k_scan2(uint32_t* __restrict__ partials,
                                                int nblocks) {
    __shared__ uint32_t sh[1024];
    int t = threadIdx.x;
    uint32_t x = (t < nblocks) ? partials[t] : 0u;
    sh[t] = x;
    __syncthreads();
    for (int off = 1; off < 1024; off <<= 1) {
        uint32_t y = (t >= off) ? sh[t - off] : 0u;
        __syncthreads();
        sh[t] += y;
        __syncthreads();
    }
    if (t < nblocks) partials[t] = sh[t] - x;
}

__global__ __launch_bounds__(1024) void k_scan3(uint32_t* __restrict__ cnt,
                                                const uint32_t* __restrict__ partials) {
    int i = blockIdx.x * 1024 + threadIdx.x;
    if (i < N_NODES) cnt[i] += partials[blockIdx.x];
}

__global__ __launch_bounds__(256) void k_place(const int* __restrict__ erow,
                                               uint32_t* __restrict__ cursor,
                                               uint32_t* __restrict__ eidx) {
    int e = blockIdx.x * 256 + threadIdx.x;
    if (e >= NNZ) return;
    int r = erow[e];
    uint32_t pos = atomicAdd(&cursor[r], 1u);
    eidx[pos] = (uint32_t)e;
}

// -------- SPMV: side[n] = sum_e vals_eff[e] * ego[col[e]]  (wave per row) ----
__global__ __launch_bounds__(256) void k_spmv(const float* __restrict__ ego,
                                              float* __restrict__ side,
                                              const uint32_t* __restrict__ cursor,
                                              const uint32_t* __restrict__ eidx,
                                              const int* __restrict__ ecol,
                                              const float* __restrict__ evals,
                                              uint32_t kn0, uint32_t kn1) {
    int lane = threadIdx.x & 63;
    int wave = (blockIdx.x * 256 + threadIdx.x) >> 6;
    int nw = (gridDim.x * 256) >> 6;
    for (int n = wave; n < N_NODES; n += nw) {
        uint32_t end = cursor[n];
        uint32_t start = (n > 0) ? cursor[n - 1] : 0u;
        float acc = 0.0f;
        for (uint32_t base = start; base < end; base += 64) {
            int m = (int)min(64u, end - base);
            int c = 0; float v = 0.0f;
            if (lane < m) {
                uint32_t ei = eidx[base + lane];
                c = ecol[ei];
                float ev = evals[ei];
                uint32_t x0 = (ei < R1M) ? ei : ei - R1M;
                uint32_t o0, o1;
                threefry2x32(kn0, kn1, x0, x0 + R1M, o0, o1);
                uint32_t bits = (ei < R1M) ? o0 : o1;
                v = (tf_uniform(bits) < 0.9f) ? ev * INVK : 0.0f;
            }
            for (int j0 = 0; j0 < m; j0 += 8) {
                int jm = min(8, m - j0);
                float g[8];
#pragma unroll
                for (int u = 0; u < 8; ++u)
                    if (u < jm) {
                        int cj = __shfl(c, j0 + u, 64);
                        g[u] = ego[(size_t)cj * 64 + lane];
                    }
#pragma unroll
                for (int u = 0; u < 8; ++u)
                    if (u < jm) {
                        float vj = __shfl(v, j0 + u, 64);
                        acc = fmaf(vj, g[u], acc);
                    }
            }
        }
        side[(size_t)n * 64 + lane] = acc;
    }
}

// -------- dense row transform, in-place on ego (row-local) ------------------
__global__ __launch_bounds__(128, 1) void k_dense(float* __restrict__ ego,
                                                  const float* __restrict__ side,
                                                  const float* __restrict__ Wg,
                                                  const float* __restrict__ bg,
                                                  const float* __restrict__ Wb,
                                                  const float* __restrict__ bb,
                                                  uint32_t km0, uint32_t km1) {
    int lane = threadIdx.x & 63;
    int wave = (blockIdx.x * 128 + threadIdx.x) >> 6;
    int nw = (gridDim.x * 128) >> 6;
    float wg[64], wb[64];
#pragma unroll
    for (int k = 0; k < 64; ++k) {
        wg[k] = Wg[k * 64 + lane];
        wb[k] = Wb[k * 64 + lane];
    }
    float bgl = bg[lane], bbl = bb[lane];
    for (int n = wave; n < N_NODES; n += nw) {
        float s = side[(size_t)n * 64 + lane];
        float e = ego[(size_t)n * 64 + lane];
        float t = e * s;
        float a1 = bgl, a2 = bbl;
#pragma unroll
        for (int k = 0; k < 64; ++k) {
            float sk = __builtin_bit_cast(float,
                __builtin_amdgcn_readlane(__builtin_bit_cast(int, s), k));
            float tk = __builtin_bit_cast(float,
                __builtin_amdgcn_readlane(__builtin_bit_cast(int, t), k));
            a1 = fmaf(sk, wg[k], a1);
            a2 = fmaf(tk, wb[k], a2);
        }
        float h = a1 + a2;
        h = (h >= 0.0f) ? h : 0.2f * h;
        uint32_t j = (uint32_t)n * 64u + (uint32_t)lane;
        uint32_t x0 = (j < HALF_MSG) ? j : j - HALF_MSG;
        uint32_t o0, o1;
        threefry2x32(km0, km1, x0, x0 + HALF_MSG, o0, o1);
        uint32_t bits = (j < HALF_MSG) ? o0 : o1;
        bool keep = tf_uniform(bits) < 0.9f;
        ego[(size_t)n * 64 + lane] = keep ? h * INVK : 0.0f;
    }
}

// ---------------- batch accumulation & finalize ----------------
__device__ inline float wred64(float v) {
#pragma unroll
    for (int m = 32; m >= 1; m >>= 1) v += __shfl_xor(v, m, 64);
    return v;
}

__global__ __launch_bounds__(256) void k_segacc(const float* __restrict__ ua,
                                                const float* __restrict__ ia,
                                                const int* __restrict__ uid,
                                                const int* __restrict__ iid,
                                                const int* __restrict__ nid,
                                                float* __restrict__ dotp,
                                                float* __restrict__ dotn,
                                                float* __restrict__ sqs,
                                                int normalize) {
    int gt = blockIdx.x * 256 + threadIdx.x;
    int w = gt >> 6, lane = gt & 63;
    if (w >= BATCH) return;
    int u = uid[w], p = iid[w], n = nid[w];
    float eu = ua[(size_t)u * EMB + lane];
    float ep = ia[(size_t)p * EMB + lane];
    float en = ia[(size_t)n * EMB + lane];
    if (normalize) {
        float su = wred64(eu * eu);
        float sp = wred64(ep * ep);
        float sn = wred64(en * en);
        eu /= fmaxf(sqrtf(su), 1e-12f);
        ep /= fmaxf(sqrtf(sp), 1e-12f);
        en /= fmaxf(sqrtf(sn), 1e-12f);
    }
    float dp = wred64(eu * ep);
    float dn = wred64(eu * en);
    float s3 = wred64(eu * eu + ep * ep + en * en);
    if (lane == 0) {
        dotp[w] += dp;
        dotn[w] += dn;
        sqs[w]  += s3;
    }
}

__global__ __launch_bounds__(256) void k_finalize(const float* __restrict__ dotp,
                                                  const float* __restrict__ dotn,
                                                  const float* __restrict__ sqs,
                                                  float* __restrict__ out) {
    __shared__ float smf[256], ssq[256];
    int t = threadIdx.x;
    float mf = 0.0f, s = 0.0f;
    for (int b = t; b < BATCH; b += 256) {
        float x = dotp[b] - dotn[b];
        float ls = fminf(x, 0.0f) - log1pf(expf(-fabsf(x)));
        mf += ls;
        s += sqs[b];
    }
    smf[t] = mf; ssq[t] = s;
    __syncthreads();
    for (int off = 128; off > 0; off >>= 1) {
        if (t < off) { smf[t] += smf[t + off]; ssq[t] += ssq[t + off]; }
        __syncthreads();
    }
    if (t == 0) {
        float mf_loss = -smf[0] / (float)BATCH;
        float reg = 0.5f * ssq[0];
        float emb_loss = (float)1e-4 * reg / (float)BATCH;
        out[0] = mf_loss + emb_loss;
        out[1] = mf_loss;
        out[2] = emb_loss;
    }
}

// ---------------- launch ----------------
extern "C" void kernel_launch(void* const* d_in, const int* in_sizes, int n_in,
                              void* d_out, int out_size, void* d_ws, size_t ws_size,
                              hipStream_t stream) {
    const int*   erow  = (const int*)d_in[0];
    const int*   ecol  = (const int*)d_in[1];
    const float* evals = (const float*)d_in[2];
    const float* uemb  = (const float*)d_in[3];
    const float* iemb  = (const float*)d_in[4];
    const int*   uid   = (const int*)d_in[5];
    const int*   iid   = (const int*)d_in[6];
    const int*   nid   = (const int*)d_in[7];
    const float* Wg[3] = {(const float*)d_in[8],  (const float*)d_in[12], (const float*)d_in[16]};
    const float* bg[3] = {(const float*)d_in[9],  (const float*)d_in[13], (const float*)d_in[17]};
    const float* Wb[3] = {(const float*)d_in[10], (const float*)d_in[14], (const float*)d_in[18]};
    const float* bb[3] = {(const float*)d_in[11], (const float*)d_in[15], (const float*)d_in[19]};

    // workspace layout (162.9 MB total — same footprint as round 2)
    float*    ego      = (float*)d_ws;                        // 19.2M f32
    float*    side     = ego + (size_t)N_NODES * EMB;         // 19.2M f32
    uint32_t* cursor   = (uint32_t*)(side + (size_t)N_NODES * EMB); // 300000
    uint32_t* eidx     = cursor + N_NODES;                    // 2M
    uint32_t* partials = eidx + NNZ;                          // 1024
    float*    dotp     = (float*)(partials + 1024);           // 4096
    float*    dotn     = dotp + BATCH;
    float*    sqs      = dotn + BATCH;
    size_t needed = ((size_t)N_NODES * EMB * 2 + N_NODES + NNZ + 1024 + 3 * BATCH) * 4;
    if (ws_size < needed) return;

    // host-side JAX key derivation: key(42) = (0,42)
    uint32_t a0, b0, a1, b1;
    threefry2x32(0u, 42u, 0u, 2u, a0, b0);   // split block 0
    threefry2x32(0u, 42u, 1u, 3u, a1, b1);   // split block 1
    uint32_t knode0 = a0, knode1 = a1;       // k_node
    uint32_t kmsg0  = b0, kmsg1  = b1;       // k_msg
    uint32_t mk[6];
    for (uint32_t k = 0; k < 3; ++k)
        threefry2x32(kmsg0, kmsg1, 0u, k, mk[2 * k], mk[2 * k + 1]);

    // init
    hipMemcpyAsync(ego, uemb, (size_t)USER_NUM * EMB * 4, hipMemcpyDeviceToDevice, stream);
    hipMemcpyAsync(ego + (size_t)USER_NUM * EMB, iemb, (size_t)ITEM_NUM * EMB * 4,
                   hipMemcpyDeviceToDevice, stream);
    hipMemsetAsync(cursor, 0, (size_t)N_NODES * 4, stream);
    hipMemsetAsync(dotp, 0, 3 * BATCH * 4, stream);

    // CSR build
    const int SCAN_BLOCKS = (N_NODES + 1023) / 1024;  // 293
    k_hist<<<(NNZ + 255) / 256, 256, 0, stream>>>(erow, cursor);
    k_scan1<<<SCAN_BLOCKS, 1024, 0, stream>>>(cursor, partials);
    k_scan2<<<1, 1024, 0, stream>>>(partials, SCAN_BLOCKS);
    k_scan3<<<SCAN_BLOCKS, 1024, 0, stream>>>(cursor, partials);
    k_place<<<(NNZ + 255) / 256, 256, 0, stream>>>(erow, cursor, eidx);

    // segment 0: raw initial embeddings, no normalization
    k_segacc<<<BATCH * 64 / 256, 256, 0, stream>>>(uemb, iemb, uid, iid, nid,
                                                   dotp, dotn, sqs, 0);

    for (int k = 0; k < 3; ++k) {
        k_spmv<<<2048, 256, 0, stream>>>(ego, side, cursor, eidx, ecol, evals,
                                         knode0, knode1);
        k_dense<<<2048, 128, 0, stream>>>(ego, side, Wg[k], bg[k], Wb[k], bb[k],
                                          mk[2 * k], mk[2 * k + 1]);
        k_segacc<<<BATCH * 64 / 256, 256, 0, stream>>>(ego, ego + (size_t)USER_NUM * EMB,
                                                       uid, iid, nid, dotp, dotn, sqs, 1);
    }
    k_finalize<<<1, 256, 0, stream>>>(dotp, dotn, sqs, (float*)d_out);
}